// Round 2
// baseline (493.971 us; speedup 1.0000x reference)
//
#include <hip/hip_runtime.h>
#include <hip/hip_cooperative_groups.h>

namespace cg = cooperative_groups;

// AdjMlp: out[r, :] = sum over edges (r, c) of weight[c, :]
// v8 = v7 fused into ONE cooperative dispatch:
//   phase 0: zero counts+ovf_n (grid-stride)      -- replaces hipMemsetAsync
//   phase 1: bucket fill (grid-stride over edges) -- was fill_k
//   phase 2: quad gather (grid-stride over row-quads, 4 rows/wave) -- was gather_k
// separated by grid.sync(). Grid clamped to co-resident capacity (occupancy API).
// Purpose: (a) remove 2 inter-dispatch drains + memset dispatch, (b) make our
// total GPU cost visible as a single dispatch in rocprof top-k (the 3-dispatch
// version hid below the harness's 64us poison fills, blocking roofline reads).
// Gather adds next-quad counts prefetch (each wave now owns ~6 quads).
// Cooperative-launch failure falls back to the verified v7 3-dispatch path.

constexpr int OUT_F = 256;
constexpr int CAP = 8;          // bucket slots per row
constexpr int MAXOVF = 16384;   // overflow edge capacity

using f32x4 = __attribute__((ext_vector_type(4))) float;
using i32x4 = __attribute__((ext_vector_type(4))) int;

// ---------------- shared device helpers ----------------

// overflow resolution: scan the (tiny) ovf list for this row, accumulate in regs
__device__ __forceinline__ void ovf_scan(f32x4& acc, int row,
                                         const int* __restrict__ ovf_n,
                                         const int* __restrict__ ovf,
                                         const f32x4* __restrict__ w4, int lane) {
    int m = *ovf_n; if (m > MAXOVF) m = MAXOVF;
    for (int j = 0; j < m; j++) {
        if (ovf[2 * j] == row)
            acc += w4[(size_t)ovf[2 * j + 1] * 64 + lane];
    }
}

// slots 2..min(n,CAP)-1 + overflow; called only when n > 2 (wave-uniform, ~8%)
__device__ __forceinline__ void rare_tail(f32x4& acc, int n, const i32x4& b0,
                                          const i32x4* __restrict__ bucket4, int row,
                                          const f32x4* __restrict__ w4, int lane,
                                          const int* __restrict__ ovf_n,
                                          const int* __restrict__ ovf) {
    int m = n < CAP ? n : CAP;
    acc += w4[(size_t)__builtin_amdgcn_readfirstlane(b0.z) * 64 + lane];
    if (m > 3) acc += w4[(size_t)__builtin_amdgcn_readfirstlane(b0.w) * 64 + lane];
    if (m > 4) {
        i32x4 b1 = __builtin_nontemporal_load(bucket4 + (size_t)row * 2 + 1);
        acc += w4[(size_t)__builtin_amdgcn_readfirstlane(b1.x) * 64 + lane];
        if (m > 5) acc += w4[(size_t)__builtin_amdgcn_readfirstlane(b1.y) * 64 + lane];
        if (m > 6) acc += w4[(size_t)__builtin_amdgcn_readfirstlane(b1.z) * 64 + lane];
        if (m > 7) acc += w4[(size_t)__builtin_amdgcn_readfirstlane(b1.w) * 64 + lane];
        if (n > CAP) ovf_scan(acc, row, ovf_n, ovf, w4, lane);
    }
}

// one quad of rows (row0..row0+3), counts already in cntv (wave-uniform)
__device__ __forceinline__ void process_quad(int row0, const i32x4& cntv,
                                             const i32x4* __restrict__ bucket4,
                                             const f32x4* __restrict__ w4,
                                             f32x4* __restrict__ out4,
                                             const int* __restrict__ ovf_n,
                                             const int* __restrict__ ovf, int lane) {
    const f32x4 z = {0.f, 0.f, 0.f, 0.f};
    const int n0 = __builtin_amdgcn_readfirstlane(cntv.x);
    const int n1 = __builtin_amdgcn_readfirstlane(cntv.y);
    const int n2 = __builtin_amdgcn_readfirstlane(cntv.z);
    const int n3 = __builtin_amdgcn_readfirstlane(cntv.w);

    f32x4* o = out4 + (size_t)row0 * 64 + lane;
    if ((n0 | n1 | n2 | n3) == 0) {
        // ~1.8% of quads: all four rows empty -> stream 4KB of zeros
        __builtin_nontemporal_store(z, o);
        __builtin_nontemporal_store(z, o + 64);
        __builtin_nontemporal_store(z, o + 128);
        __builtin_nontemporal_store(z, o + 192);
        return;
    }

    // bucket loads only for non-empty rows (scalar-predicated)
    i32x4 ba, bb, bc, bd;
    if (n0 > 0) ba = __builtin_nontemporal_load(bucket4 + (size_t)(row0 + 0) * 2);
    if (n1 > 0) bb = __builtin_nontemporal_load(bucket4 + (size_t)(row0 + 1) * 2);
    if (n2 > 0) bc = __builtin_nontemporal_load(bucket4 + (size_t)(row0 + 2) * 2);
    if (n3 > 0) bd = __builtin_nontemporal_load(bucket4 + (size_t)(row0 + 3) * 2);

    // issue all valid weight-row loads first (keeps up to 8 x 1KB in flight);
    // addresses are SGPR-base + lane*16 (cols readfirstlane'd to scalar)
    f32x4 va0, va1, vb0, vb1, vc0, vc1, vd0, vd1;
    if (n0 > 0) va0 = w4[(size_t)__builtin_amdgcn_readfirstlane(ba.x) * 64 + lane];
    if (n0 > 1) va1 = w4[(size_t)__builtin_amdgcn_readfirstlane(ba.y) * 64 + lane];
    if (n1 > 0) vb0 = w4[(size_t)__builtin_amdgcn_readfirstlane(bb.x) * 64 + lane];
    if (n1 > 1) vb1 = w4[(size_t)__builtin_amdgcn_readfirstlane(bb.y) * 64 + lane];
    if (n2 > 0) vc0 = w4[(size_t)__builtin_amdgcn_readfirstlane(bc.x) * 64 + lane];
    if (n2 > 1) vc1 = w4[(size_t)__builtin_amdgcn_readfirstlane(bc.y) * 64 + lane];
    if (n3 > 0) vd0 = w4[(size_t)__builtin_amdgcn_readfirstlane(bd.x) * 64 + lane];
    if (n3 > 1) vd1 = w4[(size_t)__builtin_amdgcn_readfirstlane(bd.y) * 64 + lane];

    f32x4 a0 = z, a1 = z, a2 = z, a3 = z;
    if (n0 > 0) {
        a0 = va0;
        if (n0 > 1) a0 += va1;
        if (n0 > 2) rare_tail(a0, n0, ba, bucket4, row0 + 0, w4, lane, ovf_n, ovf);
    }
    if (n1 > 0) {
        a1 = vb0;
        if (n1 > 1) a1 += vb1;
        if (n1 > 2) rare_tail(a1, n1, bb, bucket4, row0 + 1, w4, lane, ovf_n, ovf);
    }
    if (n2 > 0) {
        a2 = vc0;
        if (n2 > 1) a2 += vc1;
        if (n2 > 2) rare_tail(a2, n2, bc, bucket4, row0 + 2, w4, lane, ovf_n, ovf);
    }
    if (n3 > 0) {
        a3 = vd0;
        if (n3 > 1) a3 += vd1;
        if (n3 > 2) rare_tail(a3, n3, bd, bucket4, row0 + 3, w4, lane, ovf_n, ovf);
    }

    // 4KB contiguous nontemporal store per wave (write-once stream)
    __builtin_nontemporal_store(a0, o);
    __builtin_nontemporal_store(a1, o + 64);
    __builtin_nontemporal_store(a2, o + 128);
    __builtin_nontemporal_store(a3, o + 192);
}

// ---------------- fused cooperative kernel ----------------

__global__ __launch_bounds__(256) void fused_k(const int* __restrict__ rows,
                                               const int* __restrict__ cols,
                                               int* __restrict__ counts,
                                               int* __restrict__ bucket,
                                               int* __restrict__ ovf_n,
                                               int* __restrict__ ovf,
                                               const f32x4* __restrict__ w4,
                                               f32x4* __restrict__ out4,
                                               int nnz, int nrows) {
    cg::grid_group grid = cg::this_grid();
    const int tid = blockIdx.x * 256 + threadIdx.x;
    const int nthreads = gridDim.x * 256;

    // --- phase 0: zero counts[nrows] + ovf_n[4] (contiguous) ---
    for (int i = tid; i < nrows + 4; i += nthreads) counts[i] = 0;

    __threadfence();
    grid.sync();

    // --- phase 1: bucket fill ---
    for (int e = tid; e < nnz; e += nthreads) {
        int r = __builtin_nontemporal_load(rows + e);
        int c = __builtin_nontemporal_load(cols + e);
        int slot = atomicAdd(&counts[r], 1);
        if (slot < CAP) {
            bucket[r * CAP + slot] = c;
        } else {
            int o = atomicAdd(ovf_n, 1);
            if (o < MAXOVF) { ovf[2 * o] = r; ovf[2 * o + 1] = c; }
        }
    }

    __threadfence();
    grid.sync();

    // --- phase 2: quad gather, 4 rows/wave, grid-stride over quads ---
    const int lane = threadIdx.x & 63;
    int wid = (blockIdx.x << 2) + (threadIdx.x >> 6);
    wid = __builtin_amdgcn_readfirstlane(wid);
    const int nwaves = gridDim.x << 2;
    const int nquads = nrows >> 2;          // host path requires nrows % 4 == 0
    const i32x4* bucket4 = (const i32x4*)bucket;

    int q = wid;
    if (q >= nquads) return;
    i32x4 cntv = __builtin_nontemporal_load((const i32x4*)(counts + (q << 2)));
    while (true) {
        const int qn = q + nwaves;
        i32x4 cnext;
        if (qn < nquads)
            cnext = __builtin_nontemporal_load((const i32x4*)(counts + (qn << 2)));
        process_quad(q << 2, cntv, bucket4, w4, out4, ovf_n, ovf, lane);
        if (qn >= nquads) break;
        cntv = cnext;
        q = qn;
    }
}

// ---------------- v7 3-dispatch fallback kernels ----------------

__global__ __launch_bounds__(256) void fill_k(const int* __restrict__ rows,
                                              const int* __restrict__ cols,
                                              int* __restrict__ counts,
                                              int* __restrict__ bucket,
                                              int* __restrict__ ovf_n,
                                              int* __restrict__ ovf,
                                              int nnz) {
    int e = blockIdx.x * 256 + threadIdx.x;
    if (e >= nnz) return;
    int r = rows[e];
    int c = cols[e];
    int slot = atomicAdd(&counts[r], 1);
    if (slot < CAP) {
        bucket[r * CAP + slot] = c;
    } else {
        int o = atomicAdd(ovf_n, 1);
        if (o < MAXOVF) { ovf[2 * o] = r; ovf[2 * o + 1] = c; }
    }
}

__global__ __launch_bounds__(256) void gather_k(const int* __restrict__ counts,
                                                const i32x4* __restrict__ bucket4,
                                                const f32x4* __restrict__ w4,
                                                f32x4* __restrict__ out4,
                                                const int* __restrict__ ovf_n,
                                                const int* __restrict__ ovf,
                                                int nrows) {
    const int lane = threadIdx.x & 63;
    int wid = (blockIdx.x << 2) + (threadIdx.x >> 6);
    wid = __builtin_amdgcn_readfirstlane(wid);
    const int row0 = wid << 2;
    if (row0 >= nrows) return;

    if (row0 + 4 <= nrows) {
        const i32x4 cntv = __builtin_nontemporal_load((const i32x4*)(counts + row0));
        process_quad(row0, cntv, bucket4, w4, out4, ovf_n, ovf, lane);
    } else {
        const f32x4 z = {0.f, 0.f, 0.f, 0.f};
        for (int r = row0; r < nrows; r++) {
            const int n = counts[r];
            f32x4 acc = z;
            if (n > 0) {
                const i32x4 b0 = bucket4[(size_t)r * 2];
                acc += w4[(size_t)__builtin_amdgcn_readfirstlane(b0.x) * 64 + lane];
                if (n > 1) acc += w4[(size_t)__builtin_amdgcn_readfirstlane(b0.y) * 64 + lane];
                if (n > 2) rare_tail(acc, n, b0, bucket4, r, w4, lane, ovf_n, ovf);
            }
            __builtin_nontemporal_store(acc, out4 + (size_t)r * 64 + lane);
        }
    }
}

// ---------------- emergency fallback (no workspace): atomic scatter ----------

__global__ __launch_bounds__(256) void zero_f4(float4* __restrict__ out, int n4) {
    int i = blockIdx.x * 256 + threadIdx.x;
    if (i < n4) out[i] = make_float4(0.f, 0.f, 0.f, 0.f);
}

__global__ __launch_bounds__(256) void scatter_kernel(const int* __restrict__ rows,
                                                      const int* __restrict__ cols,
                                                      const float* __restrict__ weight,
                                                      float* __restrict__ out, int nnz) {
    const int lane = threadIdx.x & 63;
    const int edge = blockIdx.x * 4 + (threadIdx.x >> 6);
    if (edge >= nnz) return;
    const int r = rows[edge];
    const int c = cols[edge];
    const float4 v = ((const float4*)(weight + (size_t)c * OUT_F))[lane];
    float* o = out + (size_t)r * OUT_F + (size_t)lane * 4;
    atomicAdd(o + 0, v.x);
    atomicAdd(o + 1, v.y);
    atomicAdd(o + 2, v.z);
    atomicAdd(o + 3, v.w);
}

// ---------------- launch ----------------

extern "C" void kernel_launch(void* const* d_in, const int* in_sizes, int n_in,
                              void* d_out, int out_size, void* d_ws, size_t ws_size,
                              hipStream_t stream) {
    const int* adj = (const int*)d_in[0];          // [2, nnz] int32
    const int nnz = in_sizes[0] / 2;
    const int* rows = adj;
    const int* cols = adj + nnz;
    const float* weight = (const float*)d_in[2];   // [IN_F, 256] fp32
    float* out = (float*)d_out;                    // [nrows, 256] fp32
    const int nrows = out_size / OUT_F;

    // workspace (ints): counts[nrows] | ovf_n[4] | ovf[2*MAXOVF] | bucket[nrows*CAP]
    const size_t ovfnOff   = (size_t)nrows;                  // 16B-aligned (nrows%4==0)
    const size_t ovfOff    = ovfnOff + 4;
    const size_t bucketOff = ovfOff + 2 * MAXOVF;            // stays 16B-aligned
    const size_t need      = (bucketOff + (size_t)nrows * CAP) * 4;

    if (ws_size >= need && (nrows & 3) == 0) {
        int* wsI    = (int*)d_ws;
        int* counts = wsI;
        int* ovf_n  = wsI + ovfnOff;
        int* ovf    = wsI + ovfOff;
        int* bucket = wsI + bucketOff;

        // co-resident grid size for the cooperative launch (cached once)
        static int coopGrid = 0;
        if (coopGrid == 0) {
            int perCU = 0;
            if (hipOccupancyMaxActiveBlocksPerMultiprocessor(
                    &perCU, (const void*)fused_k, 256, 0) != hipSuccess || perCU <= 0)
                perCU = 2;                       // conservative: 2 blocks/CU always fits
            int nCU = 256;                       // MI355X default
            hipDeviceProp_t prop;
            if (hipGetDeviceProperties(&prop, 0) == hipSuccess &&
                prop.multiProcessorCount > 0)
                nCU = prop.multiProcessorCount;
            coopGrid = perCU * nCU;
        }
        int needBlocks = (nrows / 4 + 3) / 4;                // waves=nrows/4, 4/block
        int nb1 = (nnz + 255) / 256;
        if (nb1 > needBlocks) needBlocks = nb1;
        int grid = coopGrid < needBlocks ? coopGrid : needBlocks;
        if (grid < 1) grid = 1;

        const f32x4* w4v  = (const f32x4*)weight;
        f32x4*       o4v  = (f32x4*)out;
        void* kargs[] = {(void*)&rows, (void*)&cols, (void*)&counts, (void*)&bucket,
                         (void*)&ovf_n, (void*)&ovf, (void*)&w4v, (void*)&o4v,
                         (void*)&nnz, (void*)&nrows};
        hipError_t e = hipLaunchCooperativeKernel((const void*)fused_k, dim3(grid),
                                                  dim3(256), kargs, 0, stream);
        if (e == hipSuccess) return;

        // cooperative unsupported/capture-rejected: verified v7 3-dispatch path
        hipMemsetAsync(counts, 0, ovfOff * 4, stream);       // counts + ovf_n only
        fill_k<<<(nnz + 255) / 256, 256, 0, stream>>>(rows, cols, counts, bucket,
                                                      ovf_n, ovf, nnz);
        gather_k<<<(nrows + 15) / 16, 256, 0, stream>>>(counts, (const i32x4*)bucket,
                                                        (const f32x4*)weight,
                                                        (f32x4*)out, ovf_n, ovf, nrows);
    } else {
        // no usable workspace / odd shape: zero + atomic scatter (correct, slower)
        const int n4 = out_size / 4;
        zero_f4<<<(n4 + 255) / 256, 256, 0, stream>>>((float4*)out, n4);
        scatter_kernel<<<(nnz + 3) / 4, 256, 0, stream>>>(rows, cols, weight, out, nnz);
    }
}

// Round 3
// 194.209 us; speedup vs baseline: 2.5435x; 2.5435x over previous
//
#include <hip/hip_runtime.h>

// AdjMlp: out[r, :] = sum over edges (r, c) of weight[c, :]
// v9 = v6 core (unconditional clamped loads -> 8x1KB in flight; VGPR ~85 was
// the point, NOT waste) + 2-quad software pipeline per wave:
//   - all metadata for 2 quads (2 counts-vec + 8 bucket-vec, 10 NT loads)
//     issued upfront
//   - quad-B weight loads issued BEFORE quad-A stores
//   critical path: meta -> wA -> wB = 1.5 latencies/quad vs v6's 2.
// Lessons encoded: v7/v8's scalar-predicated loads collapsed to
// {load; waitcnt; use} chains (v8 VGPR=28, 311 GB/s) -- predication destroys
// MLP; dummy clamped loads are the right trade. Cooperative fusion (v8)
// regressed 2.5x -- stay with 3 dispatches.
// Measured totals (v8 counters): FETCH 51 MB + WRITE 107 MB => ~25 us floor.

constexpr int OUT_F = 256;
constexpr int CAP = 8;          // bucket slots per row
constexpr int MAXOVF = 16384;   // overflow edge capacity

using f32x4 = __attribute__((ext_vector_type(4))) float;
using i32x4 = __attribute__((ext_vector_type(4))) int;

// ---------------- build ----------------

__global__ __launch_bounds__(256) void fill_k(const int* __restrict__ rows,
                                              const int* __restrict__ cols,
                                              int* __restrict__ counts,
                                              int* __restrict__ bucket,
                                              int* __restrict__ ovf_n,
                                              int* __restrict__ ovf,
                                              int nnz) {
    int e = blockIdx.x * 256 + threadIdx.x;
    if (e >= nnz) return;
    int r = rows[e];
    int c = cols[e];
    int slot = atomicAdd(&counts[r], 1);
    if (slot < CAP) {
        bucket[r * CAP + slot] = c;
    } else {
        int o = atomicAdd(ovf_n, 1);
        if (o < MAXOVF) { ovf[2 * o] = r; ovf[2 * o + 1] = c; }
    }
}

// ---------------- gather ----------------

// overflow resolution: scan the (tiny) ovf list for this row, accumulate in regs
__device__ __forceinline__ void ovf_scan(f32x4& acc, int row,
                                         const int* __restrict__ ovf_n,
                                         const int* __restrict__ ovf,
                                         const f32x4* __restrict__ w4, int lane) {
    int m = *ovf_n; if (m > MAXOVF) m = MAXOVF;
    for (int j = 0; j < m; j++) {
        if (ovf[2 * j] == row)
            acc += w4[(size_t)ovf[2 * j + 1] * 64 + lane];
    }
}

// slots 2..min(n,CAP)-1 + overflow; called only when n > 2 (wave-uniform, ~8%)
__device__ __forceinline__ void rare_tail(f32x4& acc, int n, const i32x4& b0,
                                          const i32x4* __restrict__ bucket4, int row,
                                          const f32x4* __restrict__ w4, int lane,
                                          const int* __restrict__ ovf_n,
                                          const int* __restrict__ ovf) {
    int m = n < CAP ? n : CAP;
    acc += w4[(size_t)b0.z * 64 + lane];
    if (m > 3) acc += w4[(size_t)b0.w * 64 + lane];
    if (m > 4) {
        i32x4 b1 = __builtin_nontemporal_load(bucket4 + (size_t)row * 2 + 1);
        acc += w4[(size_t)b1.x * 64 + lane];
        if (m > 5) acc += w4[(size_t)b1.y * 64 + lane];
        if (m > 6) acc += w4[(size_t)b1.z * 64 + lane];
        if (m > 7) acc += w4[(size_t)b1.w * 64 + lane];
        if (n > CAP) ovf_scan(acc, row, ovf_n, ovf, w4, lane);
    }
}

// v6 single-quad body (used for the odd trailing quad)
__device__ __forceinline__ void quad_single(int row0,
                                            const int* __restrict__ counts,
                                            const i32x4* __restrict__ bucket4,
                                            const f32x4* __restrict__ w4,
                                            f32x4* __restrict__ out4,
                                            const int* __restrict__ ovf_n,
                                            const int* __restrict__ ovf, int lane) {
    const i32x4 cnt = __builtin_nontemporal_load((const i32x4*)(counts + row0));
    const i32x4 ba = __builtin_nontemporal_load(bucket4 + (size_t)(row0 + 0) * 2);
    const i32x4 bb = __builtin_nontemporal_load(bucket4 + (size_t)(row0 + 1) * 2);
    const i32x4 bc = __builtin_nontemporal_load(bucket4 + (size_t)(row0 + 2) * 2);
    const i32x4 bd = __builtin_nontemporal_load(bucket4 + (size_t)(row0 + 3) * 2);

    const f32x4 va0 = w4[(size_t)(cnt.x > 0 ? ba.x : 0) * 64 + lane];
    const f32x4 va1 = w4[(size_t)(cnt.x > 1 ? ba.y : 0) * 64 + lane];
    const f32x4 vb0 = w4[(size_t)(cnt.y > 0 ? bb.x : 0) * 64 + lane];
    const f32x4 vb1 = w4[(size_t)(cnt.y > 1 ? bb.y : 0) * 64 + lane];
    const f32x4 vc0 = w4[(size_t)(cnt.z > 0 ? bc.x : 0) * 64 + lane];
    const f32x4 vc1 = w4[(size_t)(cnt.z > 1 ? bc.y : 0) * 64 + lane];
    const f32x4 vd0 = w4[(size_t)(cnt.w > 0 ? bd.x : 0) * 64 + lane];
    const f32x4 vd1 = w4[(size_t)(cnt.w > 1 ? bd.y : 0) * 64 + lane];

    f32x4 a0 = {0.f, 0.f, 0.f, 0.f};
    f32x4 a1 = a0, a2 = a0, a3 = a0;
    a0 += (cnt.x > 0 ? 1.f : 0.f) * va0;
    a0 += (cnt.x > 1 ? 1.f : 0.f) * va1;
    a1 += (cnt.y > 0 ? 1.f : 0.f) * vb0;
    a1 += (cnt.y > 1 ? 1.f : 0.f) * vb1;
    a2 += (cnt.z > 0 ? 1.f : 0.f) * vc0;
    a2 += (cnt.z > 1 ? 1.f : 0.f) * vc1;
    a3 += (cnt.w > 0 ? 1.f : 0.f) * vd0;
    a3 += (cnt.w > 1 ? 1.f : 0.f) * vd1;

    if (cnt.x > 2) rare_tail(a0, cnt.x, ba, bucket4, row0 + 0, w4, lane, ovf_n, ovf);
    if (cnt.y > 2) rare_tail(a1, cnt.y, bb, bucket4, row0 + 1, w4, lane, ovf_n, ovf);
    if (cnt.z > 2) rare_tail(a2, cnt.z, bc, bucket4, row0 + 2, w4, lane, ovf_n, ovf);
    if (cnt.w > 2) rare_tail(a3, cnt.w, bd, bucket4, row0 + 3, w4, lane, ovf_n, ovf);

    __builtin_nontemporal_store(a0, out4 + (size_t)(row0 + 0) * 64 + lane);
    __builtin_nontemporal_store(a1, out4 + (size_t)(row0 + 1) * 64 + lane);
    __builtin_nontemporal_store(a2, out4 + (size_t)(row0 + 2) * 64 + lane);
    __builtin_nontemporal_store(a3, out4 + (size_t)(row0 + 3) * 64 + lane);
}

__global__ __launch_bounds__(256) void gather_k(const int* __restrict__ counts,
                                                const i32x4* __restrict__ bucket4,
                                                const f32x4* __restrict__ w4,
                                                f32x4* __restrict__ out4,
                                                const int* __restrict__ ovf_n,
                                                const int* __restrict__ ovf,
                                                int nrows) {
    const int lane = threadIdx.x & 63;
    int wid = (blockIdx.x << 2) + (threadIdx.x >> 6);
    wid = __builtin_amdgcn_readfirstlane(wid);   // wave-uniform -> scalar regs
    const int nquads = nrows >> 2;               // host path requires nrows%4==0
    const int q0 = wid << 1;                     // 2 quads (8 rows) per wave
    if (q0 >= nquads) return;
    const int rowA = q0 << 2;

    if (q0 + 1 < nquads) {
        const int rowB = rowA + 4;

        // ---- metadata for BOTH quads upfront: 10 independent NT loads ----
        const i32x4 cA = __builtin_nontemporal_load((const i32x4*)(counts + rowA));
        const i32x4 cB = __builtin_nontemporal_load((const i32x4*)(counts + rowB));
        const i32x4 Aa = __builtin_nontemporal_load(bucket4 + (size_t)(rowA + 0) * 2);
        const i32x4 Ab = __builtin_nontemporal_load(bucket4 + (size_t)(rowA + 1) * 2);
        const i32x4 Ac = __builtin_nontemporal_load(bucket4 + (size_t)(rowA + 2) * 2);
        const i32x4 Ad = __builtin_nontemporal_load(bucket4 + (size_t)(rowA + 3) * 2);
        const i32x4 Ba = __builtin_nontemporal_load(bucket4 + (size_t)(rowB + 0) * 2);
        const i32x4 Bb = __builtin_nontemporal_load(bucket4 + (size_t)(rowB + 1) * 2);
        const i32x4 Bc = __builtin_nontemporal_load(bucket4 + (size_t)(rowB + 2) * 2);
        const i32x4 Bd = __builtin_nontemporal_load(bucket4 + (size_t)(rowB + 3) * 2);

        // ---- quad A: 8 unconditional clamped weight loads (in flight) ----
        const f32x4 vA0 = w4[(size_t)(cA.x > 0 ? Aa.x : 0) * 64 + lane];
        const f32x4 vA1 = w4[(size_t)(cA.x > 1 ? Aa.y : 0) * 64 + lane];
        const f32x4 vA2 = w4[(size_t)(cA.y > 0 ? Ab.x : 0) * 64 + lane];
        const f32x4 vA3 = w4[(size_t)(cA.y > 1 ? Ab.y : 0) * 64 + lane];
        const f32x4 vA4 = w4[(size_t)(cA.z > 0 ? Ac.x : 0) * 64 + lane];
        const f32x4 vA5 = w4[(size_t)(cA.z > 1 ? Ac.y : 0) * 64 + lane];
        const f32x4 vA6 = w4[(size_t)(cA.w > 0 ? Ad.x : 0) * 64 + lane];
        const f32x4 vA7 = w4[(size_t)(cA.w > 1 ? Ad.y : 0) * 64 + lane];

        f32x4 a0 = {0.f, 0.f, 0.f, 0.f};
        f32x4 a1 = a0, a2 = a0, a3 = a0;
        a0 += (cA.x > 0 ? 1.f : 0.f) * vA0;
        a0 += (cA.x > 1 ? 1.f : 0.f) * vA1;
        a1 += (cA.y > 0 ? 1.f : 0.f) * vA2;
        a1 += (cA.y > 1 ? 1.f : 0.f) * vA3;
        a2 += (cA.z > 0 ? 1.f : 0.f) * vA4;
        a2 += (cA.z > 1 ? 1.f : 0.f) * vA5;
        a3 += (cA.w > 0 ? 1.f : 0.f) * vA6;
        a3 += (cA.w > 1 ? 1.f : 0.f) * vA7;

        if (cA.x > 2) rare_tail(a0, cA.x, Aa, bucket4, rowA + 0, w4, lane, ovf_n, ovf);
        if (cA.y > 2) rare_tail(a1, cA.y, Ab, bucket4, rowA + 1, w4, lane, ovf_n, ovf);
        if (cA.z > 2) rare_tail(a2, cA.z, Ac, bucket4, rowA + 2, w4, lane, ovf_n, ovf);
        if (cA.w > 2) rare_tail(a3, cA.w, Ad, bucket4, rowA + 3, w4, lane, ovf_n, ovf);

        // ---- quad B weight loads issued BEFORE quad A stores ----
        const f32x4 vB0 = w4[(size_t)(cB.x > 0 ? Ba.x : 0) * 64 + lane];
        const f32x4 vB1 = w4[(size_t)(cB.x > 1 ? Ba.y : 0) * 64 + lane];
        const f32x4 vB2 = w4[(size_t)(cB.y > 0 ? Bb.x : 0) * 64 + lane];
        const f32x4 vB3 = w4[(size_t)(cB.y > 1 ? Bb.y : 0) * 64 + lane];
        const f32x4 vB4 = w4[(size_t)(cB.z > 0 ? Bc.x : 0) * 64 + lane];
        const f32x4 vB5 = w4[(size_t)(cB.z > 1 ? Bc.y : 0) * 64 + lane];
        const f32x4 vB6 = w4[(size_t)(cB.w > 0 ? Bd.x : 0) * 64 + lane];
        const f32x4 vB7 = w4[(size_t)(cB.w > 1 ? Bd.y : 0) * 64 + lane];

        // quad A stores (4KB contiguous NT stream)
        f32x4* oA = out4 + (size_t)rowA * 64 + lane;
        __builtin_nontemporal_store(a0, oA);
        __builtin_nontemporal_store(a1, oA + 64);
        __builtin_nontemporal_store(a2, oA + 128);
        __builtin_nontemporal_store(a3, oA + 192);

        // ---- quad B accumulate + store ----
        f32x4 b0 = {0.f, 0.f, 0.f, 0.f};
        f32x4 b1 = b0, b2 = b0, b3 = b0;
        b0 += (cB.x > 0 ? 1.f : 0.f) * vB0;
        b0 += (cB.x > 1 ? 1.f : 0.f) * vB1;
        b1 += (cB.y > 0 ? 1.f : 0.f) * vB2;
        b1 += (cB.y > 1 ? 1.f : 0.f) * vB3;
        b2 += (cB.z > 0 ? 1.f : 0.f) * vB4;
        b2 += (cB.z > 1 ? 1.f : 0.f) * vB5;
        b3 += (cB.w > 0 ? 1.f : 0.f) * vB6;
        b3 += (cB.w > 1 ? 1.f : 0.f) * vB7;

        if (cB.x > 2) rare_tail(b0, cB.x, Ba, bucket4, rowB + 0, w4, lane, ovf_n, ovf);
        if (cB.y > 2) rare_tail(b1, cB.y, Bb, bucket4, rowB + 1, w4, lane, ovf_n, ovf);
        if (cB.z > 2) rare_tail(b2, cB.z, Bc, bucket4, rowB + 2, w4, lane, ovf_n, ovf);
        if (cB.w > 2) rare_tail(b3, cB.w, Bd, bucket4, rowB + 3, w4, lane, ovf_n, ovf);

        f32x4* oB = out4 + (size_t)rowB * 64 + lane;
        __builtin_nontemporal_store(b0, oB);
        __builtin_nontemporal_store(b1, oB + 64);
        __builtin_nontemporal_store(b2, oB + 128);
        __builtin_nontemporal_store(b3, oB + 192);
    } else {
        quad_single(rowA, counts, bucket4, w4, out4, ovf_n, ovf, lane);
    }
}

// ---------------- emergency fallback (no workspace): atomic scatter ----------

__global__ __launch_bounds__(256) void zero_f4(float4* __restrict__ out, int n4) {
    int i = blockIdx.x * 256 + threadIdx.x;
    if (i < n4) out[i] = make_float4(0.f, 0.f, 0.f, 0.f);
}

__global__ __launch_bounds__(256) void scatter_kernel(const int* __restrict__ rows,
                                                      const int* __restrict__ cols,
                                                      const float* __restrict__ weight,
                                                      float* __restrict__ out, int nnz) {
    const int lane = threadIdx.x & 63;
    const int edge = blockIdx.x * 4 + (threadIdx.x >> 6);
    if (edge >= nnz) return;
    const int r = rows[edge];
    const int c = cols[edge];
    const float4 v = ((const float4*)(weight + (size_t)c * OUT_F))[lane];
    float* o = out + (size_t)r * OUT_F + (size_t)lane * 4;
    atomicAdd(o + 0, v.x);
    atomicAdd(o + 1, v.y);
    atomicAdd(o + 2, v.z);
    atomicAdd(o + 3, v.w);
}

// ---------------- launch ----------------

extern "C" void kernel_launch(void* const* d_in, const int* in_sizes, int n_in,
                              void* d_out, int out_size, void* d_ws, size_t ws_size,
                              hipStream_t stream) {
    const int* adj = (const int*)d_in[0];          // [2, nnz] int32
    const int nnz = in_sizes[0] / 2;
    const int* rows = adj;
    const int* cols = adj + nnz;
    const float* weight = (const float*)d_in[2];   // [IN_F, 256] fp32
    float* out = (float*)d_out;                    // [nrows, 256] fp32
    const int nrows = out_size / OUT_F;

    // workspace (ints): counts[nrows] | ovf_n[4] | ovf[2*MAXOVF] | bucket[nrows*CAP]
    // only counts+ovf_n need zeroing (400KB + 16B)
    const size_t ovfnOff   = (size_t)nrows;                  // 16B-aligned (nrows%4==0)
    const size_t ovfOff    = ovfnOff + 4;
    const size_t bucketOff = ovfOff + 2 * MAXOVF;            // stays 16B-aligned
    const size_t need      = (bucketOff + (size_t)nrows * CAP) * 4;

    if (ws_size >= need && (nrows & 3) == 0) {
        int* wsI    = (int*)d_ws;
        int* counts = wsI;
        int* ovf_n  = wsI + ovfnOff;
        int* ovf    = wsI + ovfOff;
        int* bucket = wsI + bucketOff;

        hipMemsetAsync(counts, 0, ovfOff * 4, stream);       // counts + ovf_n only
        fill_k<<<(nnz + 255) / 256, 256, 0, stream>>>(rows, cols, counts, bucket,
                                                      ovf_n, ovf, nnz);
        const int nquads  = nrows >> 2;
        const int gwaves  = (nquads + 1) >> 1;               // 2 quads per wave
        const int gblocks = (gwaves + 3) >> 2;               // 4 waves per block
        gather_k<<<gblocks, 256, 0, stream>>>(counts, (const i32x4*)bucket,
                                              (const f32x4*)weight,
                                              (f32x4*)out, ovf_n, ovf, nrows);
    } else {
        // no usable workspace / odd shape: zero + atomic scatter (correct, slower)
        const int n4 = out_size / 4;
        zero_f4<<<(n4 + 255) / 256, 256, 0, stream>>>((float4*)out, n4);
        scatter_kernel<<<(nnz + 3) / 4, 256, 0, stream>>>(rows, cols, weight, out, nnz);
    }
}